// Round 13
// baseline (162.236 us; speedup 1.0000x reference)
//
#include <hip/hip_runtime.h>
#include <hip/hip_bf16.h>

// Problem constants
#define BSZ   4096
#define NOBJ  16
#define DOBS  256
#define ADIM  4
#define HID   512
#define KP1   288   // node_in (260) padded to multiple of 32 for MFMA K-loop

#define MB    16    // batch rows per block in mlp (grid = 256 -> 1 block/CU)
#define NTM   1024  // mlp threads per block (16 waves) — round-12 change
#define XP1   296   // xbar LDS row stride (u16): 592B
#define HP    520   // h1/h2 LDS row stride (u16): 1040B
#define TP    260   // t3 LDS row stride (f32): 1040B

typedef unsigned short u16;
typedef __bf16 bf16x8 __attribute__((ext_vector_type(8)));
typedef float  f32x4  __attribute__((ext_vector_type(4)));
typedef unsigned short u16x8 __attribute__((ext_vector_type(8)));
typedef unsigned short u16x4 __attribute__((ext_vector_type(4)));

static __device__ __forceinline__ u16 f2bf(float f) {
    __hip_bfloat16 h = __float2bfloat16(f);
    return __builtin_bit_cast(u16, h);
}
static __device__ __forceinline__ bf16x8 ldg8(const u16* p) {
    return __builtin_bit_cast(bf16x8, *(const u16x8*)p);
}

// ---------------------------------------------------------------------------
// K0: weight transpose+cast via LDS 32x32 tiles (coalesced both sides).
// W1 [260][512] -> W1T[512][288] (k-pad 0); W2 [512][512] -> W2T[512][512];
// W3 [512][256] -> W3T[256][512].
// ---------------------------------------------------------------------------
__global__ __launch_bounds__(256) void prep_weights(
    const float* __restrict__ W1, const float* __restrict__ W2,
    const float* __restrict__ W3,
    u16* __restrict__ W1T, u16* __restrict__ W2T, u16* __restrict__ W3T) {
    int bid = blockIdx.x;
    const float* src; u16* dst; int Ksrc, H, Kp, tk, th;
    if (bid < 144)      { src = W1; dst = W1T; Ksrc = 260; H = 512; Kp = 288; tk = bid / 16;        th = bid % 16; }
    else if (bid < 400) { src = W2; dst = W2T; Ksrc = 512; H = 512; Kp = 512; tk = (bid-144) / 16;  th = (bid-144) % 16; }
    else                { src = W3; dst = W3T; Ksrc = 512; H = 256; Kp = 512; tk = (bid-400) / 8;   th = (bid-400) % 8; }

    __shared__ float tile[32][33];
    int tx = threadIdx.x & 31, ty = threadIdx.x >> 5;   // 32 x 8
    #pragma unroll
    for (int i = 0; i < 4; ++i) {
        int k = tk * 32 + ty + i * 8;
        int h = th * 32 + tx;
        tile[ty + i * 8][tx] = (k < Ksrc) ? src[(size_t)k * H + h] : 0.f;
    }
    __syncthreads();
    #pragma unroll
    for (int i = 0; i < 4; ++i) {
        int h = th * 32 + ty + i * 8;
        int k = tk * 32 + tx;
        dst[(size_t)h * Kp + k] = f2bf(tile[tx][ty + i * 8]);
    }
}

// ---------------------------------------------------------------------------
// K1: states object-mean + one-hot tail -> xbar[4096][288] bf16 in global.
// 1024 blocks x 256 thr (4 rows/block); full-GPU occupancy for the 64MB read.
// ---------------------------------------------------------------------------
__global__ __launch_bounds__(256) void reduce_states(
    const float* __restrict__ states, const int* __restrict__ action,
    u16* __restrict__ xg) {
    int t = threadIdx.x;
    int r = blockIdx.x * 4 + (t >> 6);
    int d4 = t & 63;
    const float4* rp = (const float4*)states + (((size_t)r * NOBJ) << 6) + d4;
    float sx = 0.f, sy = 0.f, sz = 0.f, sw = 0.f;
    #pragma unroll
    for (int o = 0; o < NOBJ; ++o) {
        float4 v = rp[o << 6];
        sx += v.x; sy += v.y; sz += v.z; sw += v.w;
    }
    u16x4 st = { f2bf(sx * (1.0f / NOBJ)), f2bf(sy * (1.0f / NOBJ)),
                 f2bf(sz * (1.0f / NOBJ)), f2bf(sw * (1.0f / NOBJ)) };
    *(u16x4*)(xg + (size_t)r * KP1 + d4 * 4) = st;
    if (t < 32) {                       // one-hot tail: 4 rows x 8 chunks of 4
        int rl = t >> 3, c = t & 7;
        int r2 = blockIdx.x * 4 + rl;
        int a = action[r2] & 3;
        u16x4 v = { (u16)0, (u16)0, (u16)0, (u16)0 };
        #pragma unroll
        for (int j = 0; j < 4; ++j)
            if (c * 4 + j == a) v[j] = f2bf(1.0f / NOBJ);
        *(u16x4*)(xg + (size_t)r2 * KP1 + DOBS + c * 4) = v;
    }
}

// ---------------------------------------------------------------------------
// K2: MLP from xbar. 16 waves / 1024 threads, 16 rows/block, 256 blocks (1/CU).
// GEMM1/2: wave w owns N-cols [w*32,(w+1)*32) (nb=2); GEMM3: [w*16,(w+1)*16).
// mfma_f32_16x16x32_bf16: A lane l: row l&15, k=8*(l>>4)+j; B lane l: col l&15;
// D: col=l&15, row=4*(l>>4)+r.  (layout verified rounds 2/6/7/10/11)
// ---------------------------------------------------------------------------
__global__ __launch_bounds__(NTM) void mlp(
    const u16* __restrict__ xg,
    const u16* __restrict__ W1T, const float* __restrict__ b1,
    const u16* __restrict__ W2T, const float* __restrict__ b2,
    const u16* __restrict__ W3T, const float* __restrict__ b3,
    const float* __restrict__ lng, const float* __restrict__ lnb,
    float* __restrict__ out)
{
    __shared__ u16   xbar[MB][XP1];
    __shared__ u16   h1[MB][HP];
    __shared__ u16   h2[MB][HP];
    __shared__ float t3[MB][TP];
    __shared__ float red[2][16][MB];

    const int t  = threadIdx.x;
    const int w  = t >> 6;      // 0..15
    const int l  = t & 63;
    const int lr = l & 15;
    const int lg = l >> 4;
    const int b0 = blockIdx.x * MB;

    // ---- Phase 0': stage xbar slab (16 rows x 288 = 9216B, contiguous) ----
    {
        const u16x4* src = (const u16x4*)(xg + (size_t)b0 * KP1);
        #pragma unroll
        for (int i = t; i < MB * (KP1 / 4); i += NTM) {   // 1152 chunks
            int r = i / (KP1 / 4), c = i % (KP1 / 4);
            *(u16x4*)&xbar[r][c * 4] = src[i];
        }
    }
    __syncthreads();

    // ---- Phase 1: h1 = relu(xbar @ W1 + b1); wave cols [w*32, w*32+32) ----
    {
        f32x4 acc[2] = {};
        #pragma unroll 3
        for (int ks = 0; ks < KP1 / 32; ++ks) {
            bf16x8 a = ldg8(&xbar[lr][ks * 32 + lg * 8]);
            #pragma unroll
            for (int nb = 0; nb < 2; ++nb) {
                int n = w * 32 + nb * 16 + lr;
                bf16x8 bv = ldg8(W1T + (size_t)n * KP1 + ks * 32 + lg * 8);
                acc[nb] = __builtin_amdgcn_mfma_f32_16x16x32_bf16(a, bv, acc[nb], 0, 0, 0);
            }
        }
        #pragma unroll
        for (int nb = 0; nb < 2; ++nb) {
            int n = w * 32 + nb * 16 + lr;
            float bias = b1[n];
            #pragma unroll
            for (int r = 0; r < 4; ++r)
                h1[lg * 4 + r][n] = f2bf(fmaxf(acc[nb][r] + bias, 0.f));
        }
    }
    __syncthreads();

    // ---- Phase 2: t2 = h1 @ W2 + b2 (regs); LN + relu -> h2 ----
    {
        f32x4 acc[2] = {};
        #pragma unroll 4
        for (int ks = 0; ks < HID / 32; ++ks) {
            bf16x8 a = ldg8(&h1[lr][ks * 32 + lg * 8]);
            #pragma unroll
            for (int nb = 0; nb < 2; ++nb) {
                int n = w * 32 + nb * 16 + lr;
                bf16x8 bv = ldg8(W2T + (size_t)n * HID + ks * 32 + lg * 8);
                acc[nb] = __builtin_amdgcn_mfma_f32_16x16x32_bf16(a, bv, acc[nb], 0, 0, 0);
            }
        }
        float s1[4] = {0.f, 0.f, 0.f, 0.f}, s2[4] = {0.f, 0.f, 0.f, 0.f};
        #pragma unroll
        for (int nb = 0; nb < 2; ++nb) {
            float bias = b2[w * 32 + nb * 16 + lr];
            #pragma unroll
            for (int r = 0; r < 4; ++r) {
                float v = acc[nb][r] + bias;
                acc[nb][r] = v;
                s1[r] += v;
                s2[r] += v * v;
            }
        }
        #pragma unroll
        for (int r = 0; r < 4; ++r) {
            #pragma unroll
            for (int m = 8; m; m >>= 1) {      // reduce over lr bits (0..3)
                s1[r] += __shfl_xor(s1[r], m, 64);
                s2[r] += __shfl_xor(s2[r], m, 64);
            }
            if (lr == 0) {
                red[0][w][lg * 4 + r] = s1[r];
                red[1][w][lg * 4 + r] = s2[r];
            }
        }
        __syncthreads();
        float muv[4], rsv[4];
        #pragma unroll
        for (int r = 0; r < 4; ++r) {
            int m = lg * 4 + r;
            float S1 = 0.f, S2 = 0.f;
            #pragma unroll
            for (int ww = 0; ww < 16; ++ww) { S1 += red[0][ww][m]; S2 += red[1][ww][m]; }
            float mu = S1 * (1.0f / HID);
            float var = S2 * (1.0f / HID) - mu * mu;
            muv[r] = mu;
            rsv[r] = rsqrtf(var + 1e-5f);
        }
        #pragma unroll
        for (int nb = 0; nb < 2; ++nb) {
            int n = w * 32 + nb * 16 + lr;
            float g = lng[n], bb = lnb[n];
            #pragma unroll
            for (int r = 0; r < 4; ++r) {
                float y = (acc[nb][r] - muv[r]) * rsv[r] * g + bb;
                h2[lg * 4 + r][n] = f2bf(fmaxf(y, 0.f));
            }
        }
    }
    __syncthreads();

    // ---- Phase 3: t3 = h2 @ W3 + b3; wave cols [w*16, w*16+16) ----
    {
        f32x4 acc = {};
        #pragma unroll 4
        for (int ks = 0; ks < HID / 32; ++ks) {
            bf16x8 a = ldg8(&h2[lr][ks * 32 + lg * 8]);
            int n = w * 16 + lr;
            bf16x8 bv = ldg8(W3T + (size_t)n * HID + ks * 32 + lg * 8);
            acc = __builtin_amdgcn_mfma_f32_16x16x32_bf16(a, bv, acc, 0, 0, 0);
        }
        {
            int n = w * 16 + lr;
            float bias = b3[n];
            #pragma unroll
            for (int r = 0; r < 4; ++r)
                t3[lg * 4 + r][n] = acc[r] + bias;
        }
    }
    __syncthreads();

    // ---- Phase 4: broadcast-store out[b][o][:] = t3[b][:], float4 ----
    {
        #pragma unroll 8
        for (int i = 0; i < 16; ++i) {
            int flat = i * NTM + t;          // [r:16][o:16][d4:64] float4
            int d4 = flat & 63;
            int o  = (flat >> 6) & 15;
            int r  = flat >> 10;
            float4 v = *(const float4*)&t3[r][d4 * 4];
            *(float4*)(out + ((size_t)(b0 + r) * NOBJ + o) * DOBS + d4 * 4) = v;
        }
    }
}

// ---------------------------------------------------------------------------
extern "C" void kernel_launch(void* const* d_in, const int* in_sizes, int n_in,
                              void* d_out, int out_size, void* d_ws, size_t ws_size,
                              hipStream_t stream) {
    const float* states = (const float*)d_in[0];
    const int*   action = (const int*)d_in[1];
    const float* W1 = (const float*)d_in[2];
    const float* b1 = (const float*)d_in[3];
    const float* W2 = (const float*)d_in[4];
    const float* b2 = (const float*)d_in[5];
    const float* W3 = (const float*)d_in[6];
    const float* b3 = (const float*)d_in[7];
    const float* lng = (const float*)d_in[8];
    const float* lnb = (const float*)d_in[9];
    float* out = (float*)d_out;

    char* ws = (char*)d_ws;
    size_t off = 0;
    auto alloc = [&](size_t bytes) -> void* {
        void* p = ws + off;
        off = (off + bytes + 255) & ~(size_t)255;
        return p;
    };
    u16* W1T = (u16*)alloc((size_t)HID * KP1 * 2);
    u16* W2T = (u16*)alloc((size_t)HID * HID * 2);
    u16* W3T = (u16*)alloc((size_t)DOBS * HID * 2);
    u16* xg  = (u16*)alloc((size_t)BSZ * KP1 * 2);

    prep_weights<<<528, 256, 0, stream>>>(W1, W2, W3, W1T, W2T, W3T);
    reduce_states<<<BSZ / 4, 256, 0, stream>>>(states, action, xg);
    mlp<<<BSZ / MB, NTM, 0, stream>>>(xg, W1T, b1, W2T, b2, W3T, b3,
                                      lng, lnb, out);
}

// Round 14
// 159.450 us; speedup vs baseline: 1.0175x; 1.0175x over previous
//
#include <hip/hip_runtime.h>
#include <hip/hip_bf16.h>

// Problem constants
#define BSZ   4096
#define NOBJ  16
#define DOBS  256
#define ADIM  4
#define HID   512
#define KP1   288   // node_in (260) padded to multiple of 32 for MFMA K-loop

#define MB    16    // batch rows per block in mlp (grid = 256 -> 1 block/CU)
#define NTM   1024  // mlp threads per block (16 waves)
#define XP1   296   // xbar LDS row stride (u16): 592B
#define HP    520   // h1/h2 LDS row stride (u16): 1040B
#define TP    260   // t3 LDS row stride (f32): 1040B

typedef unsigned short u16;
typedef __bf16 bf16x8 __attribute__((ext_vector_type(8)));
typedef float  f32x4  __attribute__((ext_vector_type(4)));
typedef unsigned short u16x8 __attribute__((ext_vector_type(8)));
typedef unsigned short u16x4 __attribute__((ext_vector_type(4)));

static __device__ __forceinline__ u16 f2bf(float f) {
    __hip_bfloat16 h = __float2bfloat16(f);
    return __builtin_bit_cast(u16, h);
}
static __device__ __forceinline__ bf16x8 ldg8(const u16* p) {
    return __builtin_bit_cast(bf16x8, *(const u16x8*)p);
}

// ---------------------------------------------------------------------------
// K0: weight transpose+cast via LDS 32x32 tiles (coalesced both sides).
// ---------------------------------------------------------------------------
__global__ __launch_bounds__(256) void prep_weights(
    const float* __restrict__ W1, const float* __restrict__ W2,
    const float* __restrict__ W3,
    u16* __restrict__ W1T, u16* __restrict__ W2T, u16* __restrict__ W3T) {
    int bid = blockIdx.x;
    const float* src; u16* dst; int Ksrc, H, Kp, tk, th;
    if (bid < 144)      { src = W1; dst = W1T; Ksrc = 260; H = 512; Kp = 288; tk = bid / 16;        th = bid % 16; }
    else if (bid < 400) { src = W2; dst = W2T; Ksrc = 512; H = 512; Kp = 512; tk = (bid-144) / 16;  th = (bid-144) % 16; }
    else                { src = W3; dst = W3T; Ksrc = 512; H = 256; Kp = 512; tk = (bid-400) / 8;   th = (bid-400) % 8; }

    __shared__ float tile[32][33];
    int tx = threadIdx.x & 31, ty = threadIdx.x >> 5;   // 32 x 8
    #pragma unroll
    for (int i = 0; i < 4; ++i) {
        int k = tk * 32 + ty + i * 8;
        int h = th * 32 + tx;
        tile[ty + i * 8][tx] = (k < Ksrc) ? src[(size_t)k * H + h] : 0.f;
    }
    __syncthreads();
    #pragma unroll
    for (int i = 0; i < 4; ++i) {
        int h = th * 32 + ty + i * 8;
        int k = tk * 32 + tx;
        dst[(size_t)h * Kp + k] = f2bf(tile[tx][ty + i * 8]);
    }
}

// ---------------------------------------------------------------------------
// K1: states object-mean + one-hot tail -> xbar[4096][288] bf16 in global.
// ---------------------------------------------------------------------------
__global__ __launch_bounds__(256) void reduce_states(
    const float* __restrict__ states, const int* __restrict__ action,
    u16* __restrict__ xg) {
    int t = threadIdx.x;
    int r = blockIdx.x * 4 + (t >> 6);
    int d4 = t & 63;
    const float4* rp = (const float4*)states + (((size_t)r * NOBJ) << 6) + d4;
    float sx = 0.f, sy = 0.f, sz = 0.f, sw = 0.f;
    #pragma unroll
    for (int o = 0; o < NOBJ; ++o) {
        float4 v = rp[o << 6];
        sx += v.x; sy += v.y; sz += v.z; sw += v.w;
    }
    u16x4 st = { f2bf(sx * (1.0f / NOBJ)), f2bf(sy * (1.0f / NOBJ)),
                 f2bf(sz * (1.0f / NOBJ)), f2bf(sw * (1.0f / NOBJ)) };
    *(u16x4*)(xg + (size_t)r * KP1 + d4 * 4) = st;
    if (t < 32) {                       // one-hot tail: 4 rows x 8 chunks of 4
        int rl = t >> 3, c = t & 7;
        int r2 = blockIdx.x * 4 + rl;
        int a = action[r2] & 3;
        u16x4 v = { (u16)0, (u16)0, (u16)0, (u16)0 };
        #pragma unroll
        for (int j = 0; j < 4; ++j)
            if (c * 4 + j == a) v[j] = f2bf(1.0f / NOBJ);
        *(u16x4*)(xg + (size_t)r2 * KP1 + DOBS + c * 4) = v;
    }
}

// ---------------------------------------------------------------------------
// K2: MLP from xbar. 16 waves / 1024 threads, 16 rows/block, 256 blocks (1/CU).
// Round-14 changes (both targeting idle-pipe latency binding):
//  (1) per-block K-loop start rotation — de-hotspots L2 (all blocks otherwise
//      stream the SAME weight lines in lockstep; 32 CUs/XCD contend per line).
//      Sum order change only — numerics identical.
//  (2) full K-loop unroll — all B-loads issue ahead of the MFMA chain (MLP).
// mfma_f32_16x16x32_bf16: A lane l: row l&15, k=8*(l>>4)+j; B lane l: col l&15;
// D: col=l&15, row=4*(l>>4)+r.  (layout verified rounds 2/6/7/10/11/13)
// ---------------------------------------------------------------------------
__global__ __launch_bounds__(NTM) void mlp(
    const u16* __restrict__ xg,
    const u16* __restrict__ W1T, const float* __restrict__ b1,
    const u16* __restrict__ W2T, const float* __restrict__ b2,
    const u16* __restrict__ W3T, const float* __restrict__ b3,
    const float* __restrict__ lng, const float* __restrict__ lnb,
    float* __restrict__ out)
{
    __shared__ u16   xbar[MB][XP1];
    __shared__ u16   h1[MB][HP];
    __shared__ u16   h2[MB][HP];
    __shared__ float t3[MB][TP];
    __shared__ float red[2][16][MB];

    const int t  = threadIdx.x;
    const int w  = t >> 6;      // 0..15
    const int l  = t & 63;
    const int lr = l & 15;
    const int lg = l >> 4;
    const int b0 = blockIdx.x * MB;
    const int kr9  = blockIdx.x % 9;    // rotation for 9-step K-loop
    const int kr16 = blockIdx.x & 15;   // rotation for 16-step K-loops

    // ---- Phase 0': stage xbar slab (16 rows x 288 = 9216B, contiguous) ----
    {
        const u16x4* src = (const u16x4*)(xg + (size_t)b0 * KP1);
        #pragma unroll
        for (int i = t; i < MB * (KP1 / 4); i += NTM) {   // 1152 chunks
            int r = i / (KP1 / 4), c = i % (KP1 / 4);
            *(u16x4*)&xbar[r][c * 4] = src[i];
        }
    }
    __syncthreads();

    // ---- Phase 1: h1 = relu(xbar @ W1 + b1); wave cols [w*32, w*32+32) ----
    {
        f32x4 acc[2] = {};
        #pragma unroll
        for (int i = 0; i < KP1 / 32; ++i) {
            int ks = i + kr9; if (ks >= KP1 / 32) ks -= KP1 / 32;
            bf16x8 a = ldg8(&xbar[lr][ks * 32 + lg * 8]);
            #pragma unroll
            for (int nb = 0; nb < 2; ++nb) {
                int n = w * 32 + nb * 16 + lr;
                bf16x8 bv = ldg8(W1T + (size_t)n * KP1 + ks * 32 + lg * 8);
                acc[nb] = __builtin_amdgcn_mfma_f32_16x16x32_bf16(a, bv, acc[nb], 0, 0, 0);
            }
        }
        #pragma unroll
        for (int nb = 0; nb < 2; ++nb) {
            int n = w * 32 + nb * 16 + lr;
            float bias = b1[n];
            #pragma unroll
            for (int r = 0; r < 4; ++r)
                h1[lg * 4 + r][n] = f2bf(fmaxf(acc[nb][r] + bias, 0.f));
        }
    }
    __syncthreads();

    // ---- Phase 2: t2 = h1 @ W2 + b2 (regs); LN + relu -> h2 ----
    {
        f32x4 acc[2] = {};
        #pragma unroll
        for (int i = 0; i < HID / 32; ++i) {
            int ks = (i + kr16) & 15;
            bf16x8 a = ldg8(&h1[lr][ks * 32 + lg * 8]);
            #pragma unroll
            for (int nb = 0; nb < 2; ++nb) {
                int n = w * 32 + nb * 16 + lr;
                bf16x8 bv = ldg8(W2T + (size_t)n * HID + ks * 32 + lg * 8);
                acc[nb] = __builtin_amdgcn_mfma_f32_16x16x32_bf16(a, bv, acc[nb], 0, 0, 0);
            }
        }
        float s1[4] = {0.f, 0.f, 0.f, 0.f}, s2[4] = {0.f, 0.f, 0.f, 0.f};
        #pragma unroll
        for (int nb = 0; nb < 2; ++nb) {
            float bias = b2[w * 32 + nb * 16 + lr];
            #pragma unroll
            for (int r = 0; r < 4; ++r) {
                float v = acc[nb][r] + bias;
                acc[nb][r] = v;
                s1[r] += v;
                s2[r] += v * v;
            }
        }
        #pragma unroll
        for (int r = 0; r < 4; ++r) {
            #pragma unroll
            for (int m = 8; m; m >>= 1) {      // reduce over lr bits (0..3)
                s1[r] += __shfl_xor(s1[r], m, 64);
                s2[r] += __shfl_xor(s2[r], m, 64);
            }
            if (lr == 0) {
                red[0][w][lg * 4 + r] = s1[r];
                red[1][w][lg * 4 + r] = s2[r];
            }
        }
        __syncthreads();
        float muv[4], rsv[4];
        #pragma unroll
        for (int r = 0; r < 4; ++r) {
            int m = lg * 4 + r;
            float S1 = 0.f, S2 = 0.f;
            #pragma unroll
            for (int ww = 0; ww < 16; ++ww) { S1 += red[0][ww][m]; S2 += red[1][ww][m]; }
            float mu = S1 * (1.0f / HID);
            float var = S2 * (1.0f / HID) - mu * mu;
            muv[r] = mu;
            rsv[r] = rsqrtf(var + 1e-5f);
        }
        #pragma unroll
        for (int nb = 0; nb < 2; ++nb) {
            int n = w * 32 + nb * 16 + lr;
            float g = lng[n], bb = lnb[n];
            #pragma unroll
            for (int r = 0; r < 4; ++r) {
                float y = (acc[nb][r] - muv[r]) * rsv[r] * g + bb;
                h2[lg * 4 + r][n] = f2bf(fmaxf(y, 0.f));
            }
        }
    }
    __syncthreads();

    // ---- Phase 3: t3 = h2 @ W3 + b3; wave cols [w*16, w*16+16) ----
    {
        f32x4 acc = {};
        #pragma unroll
        for (int i = 0; i < HID / 32; ++i) {
            int ks = (i + kr16) & 15;
            bf16x8 a = ldg8(&h2[lr][ks * 32 + lg * 8]);
            int n = w * 16 + lr;
            bf16x8 bv = ldg8(W3T + (size_t)n * HID + ks * 32 + lg * 8);
            acc = __builtin_amdgcn_mfma_f32_16x16x32_bf16(a, bv, acc, 0, 0, 0);
        }
        {
            int n = w * 16 + lr;
            float bias = b3[n];
            #pragma unroll
            for (int r = 0; r < 4; ++r)
                t3[lg * 4 + r][n] = acc[r] + bias;
        }
    }
    __syncthreads();

    // ---- Phase 4: broadcast-store out[b][o][:] = t3[b][:], float4 ----
    {
        #pragma unroll 8
        for (int i = 0; i < 16; ++i) {
            int flat = i * NTM + t;          // [r:16][o:16][d4:64] float4
            int d4 = flat & 63;
            int o  = (flat >> 6) & 15;
            int r  = flat >> 10;
            float4 v = *(const float4*)&t3[r][d4 * 4];
            *(float4*)(out + ((size_t)(b0 + r) * NOBJ + o) * DOBS + d4 * 4) = v;
        }
    }
}

// ---------------------------------------------------------------------------
extern "C" void kernel_launch(void* const* d_in, const int* in_sizes, int n_in,
                              void* d_out, int out_size, void* d_ws, size_t ws_size,
                              hipStream_t stream) {
    const float* states = (const float*)d_in[0];
    const int*   action = (const int*)d_in[1];
    const float* W1 = (const float*)d_in[2];
    const float* b1 = (const float*)d_in[3];
    const float* W2 = (const float*)d_in[4];
    const float* b2 = (const float*)d_in[5];
    const float* W3 = (const float*)d_in[6];
    const float* b3 = (const float*)d_in[7];
    const float* lng = (const float*)d_in[8];
    const float* lnb = (const float*)d_in[9];
    float* out = (float*)d_out;

    char* ws = (char*)d_ws;
    size_t off = 0;
    auto alloc = [&](size_t bytes) -> void* {
        void* p = ws + off;
        off = (off + bytes + 255) & ~(size_t)255;
        return p;
    };
    u16* W1T = (u16*)alloc((size_t)HID * KP1 * 2);
    u16* W2T = (u16*)alloc((size_t)HID * HID * 2);
    u16* W3T = (u16*)alloc((size_t)DOBS * HID * 2);
    u16* xg  = (u16*)alloc((size_t)BSZ * KP1 * 2);

    prep_weights<<<528, 256, 0, stream>>>(W1, W2, W3, W1T, W2T, W3T);
    reduce_states<<<BSZ / 4, 256, 0, stream>>>(states, action, xg);
    mlp<<<BSZ / MB, NTM, 0, stream>>>(xg, W1T, b1, W2T, b2, W3T, b3,
                                      lng, lnb, out);
}